// Round 9
// baseline (514.429 us; speedup 1.0000x reference)
//
#include <hip/hip_runtime.h>
#include <hip/hip_bf16.h>

#define N_NODES 100000
#define N_EDGES 1600000
#define F_INPUT 256
#define H1DIM 64
#define H2DIM 128
#define BATCH 4096

typedef unsigned short ushort_t;

static __device__ __forceinline__ ushort_t f2bf(float f) {
    unsigned u = __float_as_uint(f);
    unsigned r = (u + 0x7FFFu + ((u >> 16) & 1u)) >> 16;  // round-to-nearest-even
    return (ushort_t)r;
}

// ---------------- degree: ONE packed 64-bit atomic per edge ----------------
// bits 40..63: edge count; bits 0..39: sum(ew) in 2^-32 fixed point.
__global__ void k_deg(const int* __restrict__ dst, const float* __restrict__ ew,
                      unsigned long long* __restrict__ degp) {
    int e = blockIdx.x * blockDim.x + threadIdx.x;
    if (e >= N_EDGES) return;
    int d = dst[e];
    unsigned long long fx = (unsigned long long)(ew[e] * 4294967296.0f);
    atomicAdd(&degp[d], (1ULL << 40) | fx);
}

__global__ void k_dis(const unsigned long long* __restrict__ degp,
                      float* __restrict__ dis, int* __restrict__ cnt) {
    int n = blockIdx.x * blockDim.x + threadIdx.x;
    if (n >= N_NODES) return;
    unsigned long long p = degp[n];
    cnt[n] = (int)(p >> 40);
    float degw = (float)((double)(p & ((1ULL << 40) - 1)) * (1.0 / 4294967296.0));
    dis[n] = rsqrtf(degw + 1.0f);  // self-loop weight 1
}

// ---------------- prefix scan (3 kernels) ----------------
__global__ void k_scan1(const int* __restrict__ cnt, int* __restrict__ rowptr,
                        int* __restrict__ bsums) {
    __shared__ int sh[256];
    int base = blockIdx.x * 1024;
    int t = threadIdx.x;
    int i0 = base + t * 4;
    int v[4];
#pragma unroll
    for (int j = 0; j < 4; ++j) {
        int i = i0 + j;
        v[j] = (i < N_NODES) ? cnt[i] : 0;
    }
    int s = v[0] + v[1] + v[2] + v[3];
    sh[t] = s;
    __syncthreads();
    for (int off = 1; off < 256; off <<= 1) {
        int xv = (t >= off) ? sh[t - off] : 0;
        __syncthreads();
        sh[t] += xv;
        __syncthreads();
    }
    int ex = sh[t] - s;
    if (t == 255) bsums[blockIdx.x] = sh[255];
    int run = ex;
#pragma unroll
    for (int j = 0; j < 4; ++j) {
        int i = i0 + j;
        if (i < N_NODES) rowptr[i] = run;
        run += v[j];
    }
}

__global__ void k_scan2(int* __restrict__ bsums, int nb) {
    if (blockIdx.x == 0 && threadIdx.x == 0) {
        int run = 0;
        for (int i = 0; i < nb; ++i) { int v = bsums[i]; bsums[i] = run; run += v; }
    }
}

__global__ void k_scan3(int* __restrict__ rowptr, const int* __restrict__ bsums,
                        int* __restrict__ woff) {
    int i = blockIdx.x * blockDim.x + threadIdx.x;
    if (i == 0) rowptr[N_NODES] = N_EDGES;
    if (i >= N_NODES) return;
    int v = rowptr[i] + bsums[i >> 10];
    rowptr[i] = v;
    woff[i] = v;
}

// ---------------- CSR fill: packed int2 record (src, norm) ----------------
__global__ void k_fill(const int* __restrict__ src, const int* __restrict__ dst,
                       const float* __restrict__ ew, const float* __restrict__ dis,
                       int* __restrict__ woff, int2* __restrict__ erec) {
    int e = blockIdx.x * blockDim.x + threadIdx.x;
    if (e >= N_EDGES) return;
    int s = src[e], d = dst[e];
    int pos = atomicAdd(&woff[d], 1);
    float nr = dis[s] * ew[e] * dis[d];
    erec[pos] = make_int2(s, __float_as_int(nr));
}

// ---------------- GEMM1: xw1[N,64] = x[N,256] @ W1[256,64], bf16 out ----------------
__global__ __launch_bounds__(256) void k_gemm1(const float* __restrict__ x,
                                               const float* __restrict__ W1,
                                               ushort_t* __restrict__ xw1b) {
    __shared__ float Ws[32 * H1DIM];   // 8KB chunk of W1
    __shared__ float As[32][68];       // transposed x chunk, padded
    int t = threadIdx.x;
    int r0 = blockIdx.x * 64;
    float acc[4][4] = {};
    int tr = t >> 4, tc = t & 15;
    for (int kc = 0; kc < 8; ++kc) {
        __syncthreads();
        for (int q = t; q < (32 * H1DIM) / 4; q += 256) {
            *(float4*)&Ws[q * 4] = *(const float4*)&W1[kc * 32 * H1DIM + q * 4];
        }
        for (int q = t; q < 512; q += 256) {
            int row = q >> 3, kg = (q & 7) * 4;
            int gr = r0 + row;
            float4 v = make_float4(0.f, 0.f, 0.f, 0.f);
            if (gr < N_NODES)
                v = *(const float4*)&x[(size_t)gr * F_INPUT + kc * 32 + kg];
            As[kg + 0][row] = v.x; As[kg + 1][row] = v.y;
            As[kg + 2][row] = v.z; As[kg + 3][row] = v.w;
        }
        __syncthreads();
#pragma unroll
        for (int k = 0; k < 32; ++k) {
            float4 a = *(float4*)&As[k][tr * 4];
            float4 b = *(float4*)&Ws[k * H1DIM + tc * 4];
            float av[4] = {a.x, a.y, a.z, a.w};
            float bv[4] = {b.x, b.y, b.z, b.w};
#pragma unroll
            for (int i = 0; i < 4; ++i)
#pragma unroll
                for (int j = 0; j < 4; ++j)
                    acc[i][j] = fmaf(av[i], bv[j], acc[i][j]);
        }
    }
#pragma unroll
    for (int i = 0; i < 4; ++i) {
        int r = r0 + tr * 4 + i;
        if (r < N_NODES) {
            ushort4 o;
            o.x = f2bf(acc[i][0]); o.y = f2bf(acc[i][1]);
            o.z = f2bf(acc[i][2]); o.w = f2bf(acc[i][3]);
            *(ushort4*)&xw1b[(size_t)r * H1DIM + tc * 4] = o;
        }
    }
}

// ---------------- agg1: h1 = relu(Ahat @ xw1 + b1) ----------------
// One wave per node; each 32-lane half processes alternating terms (self+edges).
// bf16 rows (128B), 4B loads (2 channels/lane), f32 accumulate.
__global__ __launch_bounds__(256) void k_agg1(const ushort_t* __restrict__ xw1b,
                                              const float* __restrict__ dis,
                                              const int* __restrict__ rowptr,
                                              const int2* __restrict__ erec,
                                              const float* __restrict__ b1,
                                              float* __restrict__ h1) {
    int wave = threadIdx.x >> 6, lane = threadIdx.x & 63;
    int n = blockIdx.x * 4 + wave;
    if (n >= N_NODES) return;
    int half = lane >> 5, sl = lane & 31;
    float dn = dis[n];
    int beg = rowptr[n], end = rowptr[n + 1];
    int T = end - beg + 1;  // self + neighbors
    float acc0 = 0.f, acc1 = 0.f;
    for (int t = half; t < T; t += 2) {
        int s; float m;
        if (t == 0) { s = n; m = dn * dn; }
        else { int2 r = erec[beg + t - 1]; s = r.x; m = __int_as_float(r.y); }
        unsigned u = *(const unsigned*)&xw1b[(size_t)s * H1DIM + sl * 2];
        float f0 = __uint_as_float(u << 16);
        float f1 = __uint_as_float(u & 0xFFFF0000u);
        acc0 = fmaf(m, f0, acc0);
        acc1 = fmaf(m, f1, acc1);
    }
    acc0 += __shfl_xor(acc0, 32);
    acc1 += __shfl_xor(acc1, 32);
    if (half == 0) {
        float2 o;
        o.x = fmaxf(acc0 + b1[sl * 2], 0.f);
        o.y = fmaxf(acc1 + b1[sl * 2 + 1], 0.f);
        *(float2*)&h1[(size_t)n * H1DIM + sl * 2] = o;
    }
}

// ---------------- GEMM2: xw2[N,128] = h1[N,64] @ W2[64,128] ----------------
__global__ __launch_bounds__(256) void k_gemm2(const float* __restrict__ h1,
                                               const float* __restrict__ W2,
                                               float* __restrict__ xw2) {
    __shared__ float Ws[H1DIM * H2DIM];  // 32KB
    __shared__ float As[64][68];         // 17.4KB
    int t = threadIdx.x;
    int r0 = blockIdx.x * 64;
    for (int q = t; q < (H1DIM * H2DIM) / 4; q += 256) {
        *(float4*)&Ws[q * 4] = *(const float4*)&W2[q * 4];
    }
    for (int q = t; q < 1024; q += 256) {
        int row = q >> 4, kg = (q & 15) * 4;
        int gr = r0 + row;
        float4 v = make_float4(0.f, 0.f, 0.f, 0.f);
        if (gr < N_NODES)
            v = *(const float4*)&h1[(size_t)gr * H1DIM + kg];
        As[kg + 0][row] = v.x; As[kg + 1][row] = v.y;
        As[kg + 2][row] = v.z; As[kg + 3][row] = v.w;
    }
    __syncthreads();
    float acc[4][8] = {};
    int tr = t >> 4, tc = t & 15;
#pragma unroll 8
    for (int k = 0; k < 64; ++k) {
        float4 a = *(float4*)&As[k][tr * 4];
        float4 b0 = *(float4*)&Ws[k * H2DIM + tc * 8];
        float4 b1v = *(float4*)&Ws[k * H2DIM + tc * 8 + 4];
        float av[4] = {a.x, a.y, a.z, a.w};
        float bv[8] = {b0.x, b0.y, b0.z, b0.w, b1v.x, b1v.y, b1v.z, b1v.w};
#pragma unroll
        for (int i = 0; i < 4; ++i)
#pragma unroll
            for (int j = 0; j < 8; ++j)
                acc[i][j] = fmaf(av[i], bv[j], acc[i][j]);
    }
#pragma unroll
    for (int i = 0; i < 4; ++i) {
        int r = r0 + tr * 4 + i;
        if (r < N_NODES) {
            float4 v0 = make_float4(acc[i][0], acc[i][1], acc[i][2], acc[i][3]);
            float4 v1 = make_float4(acc[i][4], acc[i][5], acc[i][6], acc[i][7]);
            *(float4*)&xw2[(size_t)r * H2DIM + tc * 8] = v0;
            *(float4*)&xw2[(size_t)r * H2DIM + tc * 8 + 4] = v1;
        }
    }
}

// ---------------- agg2 + readout: only the 4096 join rows ----------------
__global__ __launch_bounds__(256) void k_agg2(const float* __restrict__ xw2,
                                              const float* __restrict__ dis,
                                              const int* __restrict__ rowptr,
                                              const int2* __restrict__ erec,
                                              const float* __restrict__ b2,
                                              const int* __restrict__ join,
                                              const float* __restrict__ Wl,
                                              const float* __restrict__ bl,
                                              float* __restrict__ out) {
    int wave = threadIdx.x >> 6, lane = threadIdx.x & 63;
    int j = blockIdx.x * 4 + wave;
    if (j >= BATCH) return;
    int n = join[j];
    float dn = dis[n];
    float a0 = dn * dn * xw2[(size_t)n * H2DIM + lane];
    float a1 = dn * dn * xw2[(size_t)n * H2DIM + 64 + lane];
    int beg = rowptr[n], end = rowptr[n + 1];
    for (int i = beg; i < end; ++i) {
        int2 r = erec[i];
        float m = __int_as_float(r.y);
        a0 = fmaf(m, xw2[(size_t)r.x * H2DIM + lane], a0);
        a1 = fmaf(m, xw2[(size_t)r.x * H2DIM + 64 + lane], a1);
    }
    a0 += b2[lane];
    a1 += b2[64 + lane];
    float p = a0 * Wl[lane] + a1 * Wl[64 + lane];
#pragma unroll
    for (int off = 32; off > 0; off >>= 1) p += __shfl_xor(p, off);
    if (lane == 0) out[j] = 1.0f / (1.0f + expf(-(p + bl[0])));
}

extern "C" void kernel_launch(void* const* d_in, const int* in_sizes, int n_in,
                              void* d_out, int out_size, void* d_ws, size_t ws_size,
                              hipStream_t stream) {
    const float* x   = (const float*)d_in[0];
    const int*   ei  = (const int*)d_in[1];
    const int*   jix = (const int*)d_in[2];
    const float* ew  = (const float*)d_in[3];
    const float* W1  = (const float*)d_in[4];
    const float* b1  = (const float*)d_in[5];
    const float* W2  = (const float*)d_in[6];
    const float* b2  = (const float*)d_in[7];
    const float* Wl  = (const float*)d_in[8];
    const float* bl  = (const float*)d_in[9];
    float* out = (float*)d_out;
    const int* srcp = ei;
    const int* dstp = ei + N_EDGES;

    char* p = (char*)d_ws;
    auto alloc = [&](size_t bytes) {
        char* r = p;
        p += (bytes + 255) & ~(size_t)255;
        return r;
    };
    unsigned long long* degp = (unsigned long long*)alloc((size_t)N_NODES * 8);
    float* dis      = (float*)alloc((size_t)N_NODES * 4);
    int*   cnt      = (int*)alloc((size_t)(N_NODES + 1) * 4);   // reused as woff
    int*   rowptr   = (int*)alloc((size_t)(N_NODES + 1) * 4);
    int*   bsums    = (int*)alloc(1024 * 4);
    int2*  erec     = (int2*)alloc((size_t)N_EDGES * 8);
    ushort_t* xw1b  = (ushort_t*)alloc((size_t)N_NODES * H1DIM * 2);
    float* h1       = (float*)alloc((size_t)N_NODES * H1DIM * 4);
    float* xw2      = (float*)alloc((size_t)N_NODES * H2DIM * 4);

    hipMemsetAsync(degp, 0, (size_t)N_NODES * 8, stream);

    k_deg<<<(N_EDGES + 255) / 256, 256, 0, stream>>>(dstp, ew, degp);
    k_dis<<<(N_NODES + 255) / 256, 256, 0, stream>>>(degp, dis, cnt);
    int nb = (N_NODES + 1023) / 1024;
    k_scan1<<<nb, 256, 0, stream>>>(cnt, rowptr, bsums);
    k_scan2<<<1, 64, 0, stream>>>(bsums, nb);
    k_scan3<<<(N_NODES + 255) / 256, 256, 0, stream>>>(rowptr, bsums, cnt /*woff*/);
    k_fill<<<(N_EDGES + 255) / 256, 256, 0, stream>>>(srcp, dstp, ew, dis, cnt /*woff*/, erec);
    k_gemm1<<<(N_NODES + 63) / 64, 256, 0, stream>>>(x, W1, xw1b);
    k_agg1<<<(N_NODES + 3) / 4, 256, 0, stream>>>(xw1b, dis, rowptr, erec, b1, h1);
    k_gemm2<<<(N_NODES + 63) / 64, 256, 0, stream>>>(h1, W2, xw2);
    k_agg2<<<(BATCH + 3) / 4, 256, 0, stream>>>(xw2, dis, rowptr, erec, b2, jix, Wl, bl, out);
}

// Round 10
// 460.729 us; speedup vs baseline: 1.1166x; 1.1166x over previous
//
#include <hip/hip_runtime.h>
#include <hip/hip_bf16.h>

#define N_NODES 100000
#define N_EDGES 1600000
#define F_INPUT 256
#define H1DIM 64
#define H2DIM 128
#define BATCH 4096

typedef unsigned short ushort_t;

static __device__ __forceinline__ ushort_t f2bf(float f) {
    unsigned u = __float_as_uint(f);
    unsigned r = (u + 0x7FFFu + ((u >> 16) & 1u)) >> 16;  // round-to-nearest-even
    return (ushort_t)r;
}

// ---------------- degree: ONE packed 64-bit atomic per edge ----------------
// bits 40..63: edge count; bits 0..39: sum(ew) in 2^-32 fixed point.
__global__ void k_deg(const int* __restrict__ dst, const float* __restrict__ ew,
                      unsigned long long* __restrict__ degp) {
    int e = blockIdx.x * blockDim.x + threadIdx.x;
    if (e >= N_EDGES) return;
    int d = dst[e];
    unsigned long long fx = (unsigned long long)(ew[e] * 4294967296.0f);
    atomicAdd(&degp[d], (1ULL << 40) | fx);
}

__global__ void k_dis(const unsigned long long* __restrict__ degp,
                      float* __restrict__ dis, int* __restrict__ cnt) {
    int n = blockIdx.x * blockDim.x + threadIdx.x;
    if (n >= N_NODES) return;
    unsigned long long p = degp[n];
    cnt[n] = (int)(p >> 40);
    float degw = (float)((double)(p & ((1ULL << 40) - 1)) * (1.0 / 4294967296.0));
    dis[n] = rsqrtf(degw + 1.0f);  // self-loop weight 1
}

// ---------------- prefix scan (3 kernels) ----------------
__global__ void k_scan1(const int* __restrict__ cnt, int* __restrict__ rowptr,
                        int* __restrict__ bsums) {
    __shared__ int sh[256];
    int base = blockIdx.x * 1024;
    int t = threadIdx.x;
    int i0 = base + t * 4;
    int v[4];
#pragma unroll
    for (int j = 0; j < 4; ++j) {
        int i = i0 + j;
        v[j] = (i < N_NODES) ? cnt[i] : 0;
    }
    int s = v[0] + v[1] + v[2] + v[3];
    sh[t] = s;
    __syncthreads();
    for (int off = 1; off < 256; off <<= 1) {
        int xv = (t >= off) ? sh[t - off] : 0;
        __syncthreads();
        sh[t] += xv;
        __syncthreads();
    }
    int ex = sh[t] - s;
    if (t == 255) bsums[blockIdx.x] = sh[255];
    int run = ex;
#pragma unroll
    for (int j = 0; j < 4; ++j) {
        int i = i0 + j;
        if (i < N_NODES) rowptr[i] = run;
        run += v[j];
    }
}

__global__ void k_scan2(int* __restrict__ bsums, int nb) {
    if (blockIdx.x == 0 && threadIdx.x == 0) {
        int run = 0;
        for (int i = 0; i < nb; ++i) { int v = bsums[i]; bsums[i] = run; run += v; }
    }
}

__global__ void k_scan3(int* __restrict__ rowptr, const int* __restrict__ bsums,
                        int* __restrict__ woff) {
    int i = blockIdx.x * blockDim.x + threadIdx.x;
    if (i == 0) rowptr[N_NODES] = N_EDGES;
    if (i >= N_NODES) return;
    int v = rowptr[i] + bsums[i >> 10];
    rowptr[i] = v;
    woff[i] = v;
}

// ---------------- CSR fill: packed int2 record (src, norm) ----------------
__global__ void k_fill(const int* __restrict__ src, const int* __restrict__ dst,
                       const float* __restrict__ ew, const float* __restrict__ dis,
                       int* __restrict__ woff, int2* __restrict__ erec) {
    int e = blockIdx.x * blockDim.x + threadIdx.x;
    if (e >= N_EDGES) return;
    int s = src[e], d = dst[e];
    int pos = atomicAdd(&woff[d], 1);
    float nr = dis[s] * ew[e] * dis[d];
    erec[pos] = make_int2(s, __float_as_int(nr));
}

// ---------------- GEMM1: xw1[N,64] = x[N,256] @ W1[256,64], bf16 out ----------------
__global__ __launch_bounds__(256) void k_gemm1(const float* __restrict__ x,
                                               const float* __restrict__ W1,
                                               ushort_t* __restrict__ xw1b) {
    __shared__ float Ws[32 * H1DIM];   // 8KB chunk of W1
    __shared__ float As[32][68];       // transposed x chunk, padded
    int t = threadIdx.x;
    int r0 = blockIdx.x * 64;
    float acc[4][4] = {};
    int tr = t >> 4, tc = t & 15;
    for (int kc = 0; kc < 8; ++kc) {
        __syncthreads();
        for (int q = t; q < (32 * H1DIM) / 4; q += 256) {
            *(float4*)&Ws[q * 4] = *(const float4*)&W1[kc * 32 * H1DIM + q * 4];
        }
        for (int q = t; q < 512; q += 256) {
            int row = q >> 3, kg = (q & 7) * 4;
            int gr = r0 + row;
            float4 v = make_float4(0.f, 0.f, 0.f, 0.f);
            if (gr < N_NODES)
                v = *(const float4*)&x[(size_t)gr * F_INPUT + kc * 32 + kg];
            As[kg + 0][row] = v.x; As[kg + 1][row] = v.y;
            As[kg + 2][row] = v.z; As[kg + 3][row] = v.w;
        }
        __syncthreads();
#pragma unroll
        for (int k = 0; k < 32; ++k) {
            float4 a = *(float4*)&As[k][tr * 4];
            float4 b = *(float4*)&Ws[k * H1DIM + tc * 4];
            float av[4] = {a.x, a.y, a.z, a.w};
            float bv[4] = {b.x, b.y, b.z, b.w};
#pragma unroll
            for (int i = 0; i < 4; ++i)
#pragma unroll
                for (int j = 0; j < 4; ++j)
                    acc[i][j] = fmaf(av[i], bv[j], acc[i][j]);
        }
    }
#pragma unroll
    for (int i = 0; i < 4; ++i) {
        int r = r0 + tr * 4 + i;
        if (r < N_NODES) {
            ushort4 o;
            o.x = f2bf(acc[i][0]); o.y = f2bf(acc[i][1]);
            o.z = f2bf(acc[i][2]); o.w = f2bf(acc[i][3]);
            *(ushort4*)&xw1b[(size_t)r * H1DIM + tc * 4] = o;
        }
    }
}

// ---------------- agg1: h1 = relu(Ahat @ xw1 + b1) ----------------
// Latency-bound fix: quarter-wave (16 lanes x 8B = one 128B bf16 row) per term,
// 4 terms spatially in flight + 2x unroll => ~8 independent gathers in flight.
__global__ __launch_bounds__(256) void k_agg1(const ushort_t* __restrict__ xw1b,
                                              const float* __restrict__ dis,
                                              const int* __restrict__ rowptr,
                                              const int2* __restrict__ erec,
                                              const float* __restrict__ b1,
                                              float* __restrict__ h1) {
    int wave = threadIdx.x >> 6, lane = threadIdx.x & 63;
    int n = blockIdx.x * 4 + wave;
    if (n >= N_NODES) return;
    int q = lane >> 4, ql = lane & 15;   // quarter id, lane-in-quarter
    float a0 = 0.f, a1 = 0.f, a2 = 0.f, a3 = 0.f;
    int beg = rowptr[n], end = rowptr[n + 1];
    int E = end - beg;
    if (q == 0) {  // self term
        float dn = dis[n];
        float m = dn * dn;
        uint2 u = *(const uint2*)&xw1b[(size_t)n * H1DIM + ql * 4];
        a0 = fmaf(m, __uint_as_float(u.x << 16), a0);
        a1 = fmaf(m, __uint_as_float(u.x & 0xFFFF0000u), a1);
        a2 = fmaf(m, __uint_as_float(u.y << 16), a2);
        a3 = fmaf(m, __uint_as_float(u.y & 0xFFFF0000u), a3);
    }
    int e = q;
    for (; e + 4 < E; e += 8) {
        int2 r0 = erec[beg + e];
        int2 r1 = erec[beg + e + 4];
        uint2 u0 = *(const uint2*)&xw1b[(size_t)r0.x * H1DIM + ql * 4];
        uint2 u1 = *(const uint2*)&xw1b[(size_t)r1.x * H1DIM + ql * 4];
        float m0 = __int_as_float(r0.y), m1 = __int_as_float(r1.y);
        a0 = fmaf(m0, __uint_as_float(u0.x << 16), a0);
        a1 = fmaf(m0, __uint_as_float(u0.x & 0xFFFF0000u), a1);
        a2 = fmaf(m0, __uint_as_float(u0.y << 16), a2);
        a3 = fmaf(m0, __uint_as_float(u0.y & 0xFFFF0000u), a3);
        a0 = fmaf(m1, __uint_as_float(u1.x << 16), a0);
        a1 = fmaf(m1, __uint_as_float(u1.x & 0xFFFF0000u), a1);
        a2 = fmaf(m1, __uint_as_float(u1.y << 16), a2);
        a3 = fmaf(m1, __uint_as_float(u1.y & 0xFFFF0000u), a3);
    }
    if (e < E) {
        int2 r0 = erec[beg + e];
        uint2 u0 = *(const uint2*)&xw1b[(size_t)r0.x * H1DIM + ql * 4];
        float m0 = __int_as_float(r0.y);
        a0 = fmaf(m0, __uint_as_float(u0.x << 16), a0);
        a1 = fmaf(m0, __uint_as_float(u0.x & 0xFFFF0000u), a1);
        a2 = fmaf(m0, __uint_as_float(u0.y << 16), a2);
        a3 = fmaf(m0, __uint_as_float(u0.y & 0xFFFF0000u), a3);
    }
    // reduce across the 4 quarters (lanes ql, ql+16, ql+32, ql+48)
    a0 += __shfl_xor(a0, 16); a0 += __shfl_xor(a0, 32);
    a1 += __shfl_xor(a1, 16); a1 += __shfl_xor(a1, 32);
    a2 += __shfl_xor(a2, 16); a2 += __shfl_xor(a2, 32);
    a3 += __shfl_xor(a3, 16); a3 += __shfl_xor(a3, 32);
    if (q == 0) {
        float4 o;
        o.x = fmaxf(a0 + b1[ql * 4 + 0], 0.f);
        o.y = fmaxf(a1 + b1[ql * 4 + 1], 0.f);
        o.z = fmaxf(a2 + b1[ql * 4 + 2], 0.f);
        o.w = fmaxf(a3 + b1[ql * 4 + 3], 0.f);
        *(float4*)&h1[(size_t)n * H1DIM + ql * 4] = o;
    }
}

// ---------------- GEMM2: xw2[N,128] = h1[N,64] @ W2[64,128] ----------------
__global__ __launch_bounds__(256) void k_gemm2(const float* __restrict__ h1,
                                               const float* __restrict__ W2,
                                               float* __restrict__ xw2) {
    __shared__ float Ws[H1DIM * H2DIM];  // 32KB
    __shared__ float As[64][68];         // 17.4KB
    int t = threadIdx.x;
    int r0 = blockIdx.x * 64;
    for (int q = t; q < (H1DIM * H2DIM) / 4; q += 256) {
        *(float4*)&Ws[q * 4] = *(const float4*)&W2[q * 4];
    }
    for (int q = t; q < 1024; q += 256) {
        int row = q >> 4, kg = (q & 15) * 4;
        int gr = r0 + row;
        float4 v = make_float4(0.f, 0.f, 0.f, 0.f);
        if (gr < N_NODES)
            v = *(const float4*)&h1[(size_t)gr * H1DIM + kg];
        As[kg + 0][row] = v.x; As[kg + 1][row] = v.y;
        As[kg + 2][row] = v.z; As[kg + 3][row] = v.w;
    }
    __syncthreads();
    float acc[4][8] = {};
    int tr = t >> 4, tc = t & 15;
#pragma unroll 8
    for (int k = 0; k < 64; ++k) {
        float4 a = *(float4*)&As[k][tr * 4];
        float4 b0 = *(float4*)&Ws[k * H2DIM + tc * 8];
        float4 b1v = *(float4*)&Ws[k * H2DIM + tc * 8 + 4];
        float av[4] = {a.x, a.y, a.z, a.w};
        float bv[8] = {b0.x, b0.y, b0.z, b0.w, b1v.x, b1v.y, b1v.z, b1v.w};
#pragma unroll
        for (int i = 0; i < 4; ++i)
#pragma unroll
            for (int j = 0; j < 8; ++j)
                acc[i][j] = fmaf(av[i], bv[j], acc[i][j]);
    }
#pragma unroll
    for (int i = 0; i < 4; ++i) {
        int r = r0 + tr * 4 + i;
        if (r < N_NODES) {
            float4 v0 = make_float4(acc[i][0], acc[i][1], acc[i][2], acc[i][3]);
            float4 v1 = make_float4(acc[i][4], acc[i][5], acc[i][6], acc[i][7]);
            *(float4*)&xw2[(size_t)r * H2DIM + tc * 8] = v0;
            *(float4*)&xw2[(size_t)r * H2DIM + tc * 8 + 4] = v1;
        }
    }
}

// ---------------- agg2 + readout: only the 4096 join rows ----------------
__global__ __launch_bounds__(256) void k_agg2(const float* __restrict__ xw2,
                                              const float* __restrict__ dis,
                                              const int* __restrict__ rowptr,
                                              const int2* __restrict__ erec,
                                              const float* __restrict__ b2,
                                              const int* __restrict__ join,
                                              const float* __restrict__ Wl,
                                              const float* __restrict__ bl,
                                              float* __restrict__ out) {
    int wave = threadIdx.x >> 6, lane = threadIdx.x & 63;
    int j = blockIdx.x * 4 + wave;
    if (j >= BATCH) return;
    int n = join[j];
    float dn = dis[n];
    float a0 = dn * dn * xw2[(size_t)n * H2DIM + lane];
    float a1 = dn * dn * xw2[(size_t)n * H2DIM + 64 + lane];
    int beg = rowptr[n], end = rowptr[n + 1];
    for (int i = beg; i < end; ++i) {
        int2 r = erec[i];
        float m = __int_as_float(r.y);
        a0 = fmaf(m, xw2[(size_t)r.x * H2DIM + lane], a0);
        a1 = fmaf(m, xw2[(size_t)r.x * H2DIM + 64 + lane], a1);
    }
    a0 += b2[lane];
    a1 += b2[64 + lane];
    float p = a0 * Wl[lane] + a1 * Wl[64 + lane];
#pragma unroll
    for (int off = 32; off > 0; off >>= 1) p += __shfl_xor(p, off);
    if (lane == 0) out[j] = 1.0f / (1.0f + expf(-(p + bl[0])));
}

extern "C" void kernel_launch(void* const* d_in, const int* in_sizes, int n_in,
                              void* d_out, int out_size, void* d_ws, size_t ws_size,
                              hipStream_t stream) {
    const float* x   = (const float*)d_in[0];
    const int*   ei  = (const int*)d_in[1];
    const int*   jix = (const int*)d_in[2];
    const float* ew  = (const float*)d_in[3];
    const float* W1  = (const float*)d_in[4];
    const float* b1  = (const float*)d_in[5];
    const float* W2  = (const float*)d_in[6];
    const float* b2  = (const float*)d_in[7];
    const float* Wl  = (const float*)d_in[8];
    const float* bl  = (const float*)d_in[9];
    float* out = (float*)d_out;
    const int* srcp = ei;
    const int* dstp = ei + N_EDGES;

    char* p = (char*)d_ws;
    auto alloc = [&](size_t bytes) {
        char* r = p;
        p += (bytes + 255) & ~(size_t)255;
        return r;
    };
    unsigned long long* degp = (unsigned long long*)alloc((size_t)N_NODES * 8);
    float* dis      = (float*)alloc((size_t)N_NODES * 4);
    int*   cnt      = (int*)alloc((size_t)(N_NODES + 1) * 4);   // reused as woff
    int*   rowptr   = (int*)alloc((size_t)(N_NODES + 1) * 4);
    int*   bsums    = (int*)alloc(1024 * 4);
    int2*  erec     = (int2*)alloc((size_t)N_EDGES * 8);
    ushort_t* xw1b  = (ushort_t*)alloc((size_t)N_NODES * H1DIM * 2);
    float* h1       = (float*)alloc((size_t)N_NODES * H1DIM * 4);
    float* xw2      = (float*)alloc((size_t)N_NODES * H2DIM * 4);

    hipMemsetAsync(degp, 0, (size_t)N_NODES * 8, stream);

    k_deg<<<(N_EDGES + 255) / 256, 256, 0, stream>>>(dstp, ew, degp);
    k_dis<<<(N_NODES + 255) / 256, 256, 0, stream>>>(degp, dis, cnt);
    int nb = (N_NODES + 1023) / 1024;
    k_scan1<<<nb, 256, 0, stream>>>(cnt, rowptr, bsums);
    k_scan2<<<1, 64, 0, stream>>>(bsums, nb);
    k_scan3<<<(N_NODES + 255) / 256, 256, 0, stream>>>(rowptr, bsums, cnt /*woff*/);
    k_fill<<<(N_EDGES + 255) / 256, 256, 0, stream>>>(srcp, dstp, ew, dis, cnt /*woff*/, erec);
    k_gemm1<<<(N_NODES + 63) / 64, 256, 0, stream>>>(x, W1, xw1b);
    k_agg1<<<(N_NODES + 3) / 4, 256, 0, stream>>>(xw1b, dis, rowptr, erec, b1, h1);
    k_gemm2<<<(N_NODES + 63) / 64, 256, 0, stream>>>(h1, W2, xw2);
    k_agg2<<<(BATCH + 3) / 4, 256, 0, stream>>>(xw2, dis, rowptr, erec, b2, jix, Wl, bl, out);
}

// Round 11
// 404.180 us; speedup vs baseline: 1.2728x; 1.1399x over previous
//
#include <hip/hip_runtime.h>
#include <hip/hip_bf16.h>

#define N_NODES 100000
#define N_EDGES 1600000
#define F_INPUT 256
#define H1DIM 64
#define H2DIM 128
#define BATCH 4096

// bucketed CSR build: 782 buckets of 128 nodes (dst >> 7)
#define NB 782
#define BSHIFT 7
#define BNODES 128

typedef unsigned short ushort_t;

static __device__ __forceinline__ ushort_t f2bf(float f) {
    unsigned u = __float_as_uint(f);
    unsigned r = (u + 0x7FFFu + ((u >> 16) & 1u)) >> 16;  // round-to-nearest-even
    return (ushort_t)r;
}

// ---------------- pass A: bucket histogram (LDS-aggregated) ----------------
__global__ __launch_bounds__(256) void k_hist(const int* __restrict__ dst,
                                              unsigned* __restrict__ gcnt) {
    __shared__ unsigned h[NB];
    int t = threadIdx.x;
    for (int i = t; i < NB; i += 256) h[i] = 0;
    __syncthreads();
    const int EPB = (N_EDGES + gridDim.x - 1) / gridDim.x;
    int b0 = blockIdx.x * EPB, b1 = min(b0 + EPB, N_EDGES);
    for (int e = b0 + t; e < b1; e += 256)
        atomicAdd(&h[((unsigned)dst[e]) >> BSHIFT], 1u);
    __syncthreads();
    for (int i = t; i < NB; i += 256)
        if (h[i]) atomicAdd(&gcnt[i], h[i]);
}

// ---------------- pass B: scan bucket counts (one block) ----------------
__global__ __launch_bounds__(256) void k_bscan(const unsigned* __restrict__ gcnt,
                                               int* __restrict__ bptr,
                                               int* __restrict__ bcur) {
    __shared__ int sh[256];
    int t = threadIdx.x;
    int i0 = t * 4;
    int v[4];
#pragma unroll
    for (int j = 0; j < 4; ++j) v[j] = (i0 + j < NB) ? (int)gcnt[i0 + j] : 0;
    int s = v[0] + v[1] + v[2] + v[3];
    sh[t] = s;
    __syncthreads();
    for (int off = 1; off < 256; off <<= 1) {
        int xv = (t >= off) ? sh[t - off] : 0;
        __syncthreads();
        sh[t] += xv;
        __syncthreads();
    }
    int run = sh[t] - s;
#pragma unroll
    for (int j = 0; j < 4; ++j) {
        int i = i0 + j;
        if (i < NB) { bptr[i] = run; bcur[i] = run; }
        run += v[j];
    }
    if (t == 255) bptr[NB] = N_EDGES;
}

// ---------------- pass C: scatter edges into bucket regions ----------------
// record: (src | dstlocal<<17, ew-bits); src < 2^17, dstlocal < 2^7.
__global__ __launch_bounds__(256) void k_bscatter(const int* __restrict__ src,
                                                  const int* __restrict__ dst,
                                                  const float* __restrict__ ew,
                                                  int* __restrict__ bcur,
                                                  int2* __restrict__ bes) {
    __shared__ unsigned h[NB];
    __shared__ int cur[NB];
    int t = threadIdx.x;
    for (int i = t; i < NB; i += 256) h[i] = 0;
    __syncthreads();
    const int EPB = (N_EDGES + gridDim.x - 1) / gridDim.x;
    int b0 = blockIdx.x * EPB, b1 = min(b0 + EPB, N_EDGES);
    for (int e = b0 + t; e < b1; e += 256)
        atomicAdd(&h[((unsigned)dst[e]) >> BSHIFT], 1u);
    __syncthreads();
    for (int i = t; i < NB; i += 256)
        cur[i] = h[i] ? atomicAdd(&bcur[i], (int)h[i]) : 0;
    __syncthreads();
    for (int e = b0 + t; e < b1; e += 256) {
        int d = dst[e];
        int bk = ((unsigned)d) >> BSHIFT;
        int pos = atomicAdd(&cur[bk], 1);
        int packed = src[e] | ((d & (BNODES - 1)) << 17);
        bes[pos] = make_int2(packed, __float_as_int(ew[e]));
    }
}

// ---------------- pass D: per-bucket degree -> cnt + dis ----------------
__global__ __launch_bounds__(256) void k_bdeg(const int* __restrict__ bptr,
                                              const int2* __restrict__ bes,
                                              int* __restrict__ cnt,
                                              float* __restrict__ dis) {
    __shared__ unsigned cntL[BNODES];
    __shared__ float degL[BNODES];
    int b = blockIdx.x, t = threadIdx.x;
    if (t < BNODES) { cntL[t] = 0u; degL[t] = 0.f; }
    __syncthreads();
    int e0 = bptr[b], e1 = bptr[b + 1];
    for (int e = e0 + t; e < e1; e += 256) {
        int2 r = bes[e];
        int dl = (r.x >> 17) & (BNODES - 1);
        atomicAdd(&cntL[dl], 1u);
        atomicAdd(&degL[dl], __int_as_float(r.y));
    }
    __syncthreads();
    int node = b * BNODES + t;
    if (t < BNODES && node < N_NODES) {
        cnt[node] = (int)cntL[t];
        dis[node] = rsqrtf(degL[t] + 1.0f);  // self-loop weight 1
    }
}

// ---------------- rowptr scan over nodes (3 kernels, as before) ----------------
__global__ void k_scan1(const int* __restrict__ cnt, int* __restrict__ rowptr,
                        int* __restrict__ bsums) {
    __shared__ int sh[256];
    int base = blockIdx.x * 1024;
    int t = threadIdx.x;
    int i0 = base + t * 4;
    int v[4];
#pragma unroll
    for (int j = 0; j < 4; ++j) {
        int i = i0 + j;
        v[j] = (i < N_NODES) ? cnt[i] : 0;
    }
    int s = v[0] + v[1] + v[2] + v[3];
    sh[t] = s;
    __syncthreads();
    for (int off = 1; off < 256; off <<= 1) {
        int xv = (t >= off) ? sh[t - off] : 0;
        __syncthreads();
        sh[t] += xv;
        __syncthreads();
    }
    int ex = sh[t] - s;
    if (t == 255) bsums[blockIdx.x] = sh[255];
    int run = ex;
#pragma unroll
    for (int j = 0; j < 4; ++j) {
        int i = i0 + j;
        if (i < N_NODES) rowptr[i] = run;
        run += v[j];
    }
}

__global__ void k_scan2(int* __restrict__ bsums, int nb) {
    if (blockIdx.x == 0 && threadIdx.x == 0) {
        int run = 0;
        for (int i = 0; i < nb; ++i) { int v = bsums[i]; bsums[i] = run; run += v; }
    }
}

__global__ void k_scan3(int* __restrict__ rowptr, const int* __restrict__ bsums) {
    int i = blockIdx.x * blockDim.x + threadIdx.x;
    if (i == 0) rowptr[N_NODES] = N_EDGES;
    if (i >= N_NODES) return;
    rowptr[i] = rowptr[i] + bsums[i >> 10];
}

// ---------------- pass E: per-bucket final CSR scatter + norm ----------------
__global__ __launch_bounds__(256) void k_bfinal(const int* __restrict__ bptr,
                                                const int* __restrict__ rowptr,
                                                const int2* __restrict__ bes,
                                                const float* __restrict__ dis,
                                                int2* __restrict__ erec) {
    __shared__ int cur[BNODES];
    int b = blockIdx.x, t = threadIdx.x;
    int nbase = b * BNODES;
    if (t < BNODES && nbase + t < N_NODES) cur[t] = rowptr[nbase + t];
    __syncthreads();
    int e0 = bptr[b], e1 = bptr[b + 1];
    for (int e = e0 + t; e < e1; e += 256) {
        int2 r = bes[e];
        int s = r.x & 0x1FFFF;
        int dl = (r.x >> 17) & (BNODES - 1);
        float nr = dis[s] * __int_as_float(r.y) * dis[nbase + dl];
        int pos = atomicAdd(&cur[dl], 1);
        erec[pos] = make_int2(s, __float_as_int(nr));
    }
}

// ---------------- GEMM1: xw1[N,64] = x[N,256] @ W1[256,64], bf16 out ----------------
__global__ __launch_bounds__(256) void k_gemm1(const float* __restrict__ x,
                                               const float* __restrict__ W1,
                                               ushort_t* __restrict__ xw1b) {
    __shared__ float Ws[32 * H1DIM];   // 8KB chunk of W1
    __shared__ float As[32][68];       // transposed x chunk, padded
    int t = threadIdx.x;
    int r0 = blockIdx.x * 64;
    float acc[4][4] = {};
    int tr = t >> 4, tc = t & 15;
    for (int kc = 0; kc < 8; ++kc) {
        __syncthreads();
        for (int q = t; q < (32 * H1DIM) / 4; q += 256) {
            *(float4*)&Ws[q * 4] = *(const float4*)&W1[kc * 32 * H1DIM + q * 4];
        }
        for (int q = t; q < 512; q += 256) {
            int row = q >> 3, kg = (q & 7) * 4;
            int gr = r0 + row;
            float4 v = make_float4(0.f, 0.f, 0.f, 0.f);
            if (gr < N_NODES)
                v = *(const float4*)&x[(size_t)gr * F_INPUT + kc * 32 + kg];
            As[kg + 0][row] = v.x; As[kg + 1][row] = v.y;
            As[kg + 2][row] = v.z; As[kg + 3][row] = v.w;
        }
        __syncthreads();
#pragma unroll
        for (int k = 0; k < 32; ++k) {
            float4 a = *(float4*)&As[k][tr * 4];
            float4 b = *(float4*)&Ws[k * H1DIM + tc * 4];
            float av[4] = {a.x, a.y, a.z, a.w};
            float bv[4] = {b.x, b.y, b.z, b.w};
#pragma unroll
            for (int i = 0; i < 4; ++i)
#pragma unroll
                for (int j = 0; j < 4; ++j)
                    acc[i][j] = fmaf(av[i], bv[j], acc[i][j]);
        }
    }
#pragma unroll
    for (int i = 0; i < 4; ++i) {
        int r = r0 + tr * 4 + i;
        if (r < N_NODES) {
            ushort4 o;
            o.x = f2bf(acc[i][0]); o.y = f2bf(acc[i][1]);
            o.z = f2bf(acc[i][2]); o.w = f2bf(acc[i][3]);
            *(ushort4*)&xw1b[(size_t)r * H1DIM + tc * 4] = o;
        }
    }
}

// ---------------- agg1: h1 = relu(Ahat @ xw1 + b1) ----------------
// quarter-wave (16 lanes x 8B = one 128B bf16 row) per term, 2x unroll.
__global__ __launch_bounds__(256) void k_agg1(const ushort_t* __restrict__ xw1b,
                                              const float* __restrict__ dis,
                                              const int* __restrict__ rowptr,
                                              const int2* __restrict__ erec,
                                              const float* __restrict__ b1,
                                              float* __restrict__ h1) {
    int wave = threadIdx.x >> 6, lane = threadIdx.x & 63;
    int n = blockIdx.x * 4 + wave;
    if (n >= N_NODES) return;
    int q = lane >> 4, ql = lane & 15;   // quarter id, lane-in-quarter
    float a0 = 0.f, a1 = 0.f, a2 = 0.f, a3 = 0.f;
    int beg = rowptr[n], end = rowptr[n + 1];
    int E = end - beg;
    if (q == 0) {  // self term
        float dn = dis[n];
        float m = dn * dn;
        uint2 u = *(const uint2*)&xw1b[(size_t)n * H1DIM + ql * 4];
        a0 = fmaf(m, __uint_as_float(u.x << 16), a0);
        a1 = fmaf(m, __uint_as_float(u.x & 0xFFFF0000u), a1);
        a2 = fmaf(m, __uint_as_float(u.y << 16), a2);
        a3 = fmaf(m, __uint_as_float(u.y & 0xFFFF0000u), a3);
    }
    int e = q;
    for (; e + 4 < E; e += 8) {
        int2 r0 = erec[beg + e];
        int2 r1 = erec[beg + e + 4];
        uint2 u0 = *(const uint2*)&xw1b[(size_t)r0.x * H1DIM + ql * 4];
        uint2 u1 = *(const uint2*)&xw1b[(size_t)r1.x * H1DIM + ql * 4];
        float m0 = __int_as_float(r0.y), m1 = __int_as_float(r1.y);
        a0 = fmaf(m0, __uint_as_float(u0.x << 16), a0);
        a1 = fmaf(m0, __uint_as_float(u0.x & 0xFFFF0000u), a1);
        a2 = fmaf(m0, __uint_as_float(u0.y << 16), a2);
        a3 = fmaf(m0, __uint_as_float(u0.y & 0xFFFF0000u), a3);
        a0 = fmaf(m1, __uint_as_float(u1.x << 16), a0);
        a1 = fmaf(m1, __uint_as_float(u1.x & 0xFFFF0000u), a1);
        a2 = fmaf(m1, __uint_as_float(u1.y << 16), a2);
        a3 = fmaf(m1, __uint_as_float(u1.y & 0xFFFF0000u), a3);
    }
    if (e < E) {
        int2 r0 = erec[beg + e];
        uint2 u0 = *(const uint2*)&xw1b[(size_t)r0.x * H1DIM + ql * 4];
        float m0 = __int_as_float(r0.y);
        a0 = fmaf(m0, __uint_as_float(u0.x << 16), a0);
        a1 = fmaf(m0, __uint_as_float(u0.x & 0xFFFF0000u), a1);
        a2 = fmaf(m0, __uint_as_float(u0.y << 16), a2);
        a3 = fmaf(m0, __uint_as_float(u0.y & 0xFFFF0000u), a3);
    }
    a0 += __shfl_xor(a0, 16); a0 += __shfl_xor(a0, 32);
    a1 += __shfl_xor(a1, 16); a1 += __shfl_xor(a1, 32);
    a2 += __shfl_xor(a2, 16); a2 += __shfl_xor(a2, 32);
    a3 += __shfl_xor(a3, 16); a3 += __shfl_xor(a3, 32);
    if (q == 0) {
        float4 o;
        o.x = fmaxf(a0 + b1[ql * 4 + 0], 0.f);
        o.y = fmaxf(a1 + b1[ql * 4 + 1], 0.f);
        o.z = fmaxf(a2 + b1[ql * 4 + 2], 0.f);
        o.w = fmaxf(a3 + b1[ql * 4 + 3], 0.f);
        *(float4*)&h1[(size_t)n * H1DIM + ql * 4] = o;
    }
}

// ---------------- GEMM2: xw2[N,128] = h1[N,64] @ W2[64,128] ----------------
__global__ __launch_bounds__(256) void k_gemm2(const float* __restrict__ h1,
                                               const float* __restrict__ W2,
                                               float* __restrict__ xw2) {
    __shared__ float Ws[H1DIM * H2DIM];  // 32KB
    __shared__ float As[64][68];         // 17.4KB
    int t = threadIdx.x;
    int r0 = blockIdx.x * 64;
    for (int q = t; q < (H1DIM * H2DIM) / 4; q += 256) {
        *(float4*)&Ws[q * 4] = *(const float4*)&W2[q * 4];
    }
    for (int q = t; q < 1024; q += 256) {
        int row = q >> 4, kg = (q & 15) * 4;
        int gr = r0 + row;
        float4 v = make_float4(0.f, 0.f, 0.f, 0.f);
        if (gr < N_NODES)
            v = *(const float4*)&h1[(size_t)gr * H1DIM + kg];
        As[kg + 0][row] = v.x; As[kg + 1][row] = v.y;
        As[kg + 2][row] = v.z; As[kg + 3][row] = v.w;
    }
    __syncthreads();
    float acc[4][8] = {};
    int tr = t >> 4, tc = t & 15;
#pragma unroll 8
    for (int k = 0; k < 64; ++k) {
        float4 a = *(float4*)&As[k][tr * 4];
        float4 b0 = *(float4*)&Ws[k * H2DIM + tc * 8];
        float4 b1v = *(float4*)&Ws[k * H2DIM + tc * 8 + 4];
        float av[4] = {a.x, a.y, a.z, a.w};
        float bv[8] = {b0.x, b0.y, b0.z, b0.w, b1v.x, b1v.y, b1v.z, b1v.w};
#pragma unroll
        for (int i = 0; i < 4; ++i)
#pragma unroll
            for (int j = 0; j < 8; ++j)
                acc[i][j] = fmaf(av[i], bv[j], acc[i][j]);
    }
#pragma unroll
    for (int i = 0; i < 4; ++i) {
        int r = r0 + tr * 4 + i;
        if (r < N_NODES) {
            float4 v0 = make_float4(acc[i][0], acc[i][1], acc[i][2], acc[i][3]);
            float4 v1 = make_float4(acc[i][4], acc[i][5], acc[i][6], acc[i][7]);
            *(float4*)&xw2[(size_t)r * H2DIM + tc * 8] = v0;
            *(float4*)&xw2[(size_t)r * H2DIM + tc * 8 + 4] = v1;
        }
    }
}

// ---------------- agg2 + readout: only the 4096 join rows ----------------
__global__ __launch_bounds__(256) void k_agg2(const float* __restrict__ xw2,
                                              const float* __restrict__ dis,
                                              const int* __restrict__ rowptr,
                                              const int2* __restrict__ erec,
                                              const float* __restrict__ b2,
                                              const int* __restrict__ join,
                                              const float* __restrict__ Wl,
                                              const float* __restrict__ bl,
                                              float* __restrict__ out) {
    int wave = threadIdx.x >> 6, lane = threadIdx.x & 63;
    int j = blockIdx.x * 4 + wave;
    if (j >= BATCH) return;
    int n = join[j];
    float dn = dis[n];
    float a0 = dn * dn * xw2[(size_t)n * H2DIM + lane];
    float a1 = dn * dn * xw2[(size_t)n * H2DIM + 64 + lane];
    int beg = rowptr[n], end = rowptr[n + 1];
    for (int i = beg; i < end; ++i) {
        int2 r = erec[i];
        float m = __int_as_float(r.y);
        a0 = fmaf(m, xw2[(size_t)r.x * H2DIM + lane], a0);
        a1 = fmaf(m, xw2[(size_t)r.x * H2DIM + 64 + lane], a1);
    }
    a0 += b2[lane];
    a1 += b2[64 + lane];
    float p = a0 * Wl[lane] + a1 * Wl[64 + lane];
#pragma unroll
    for (int off = 32; off > 0; off >>= 1) p += __shfl_xor(p, off);
    if (lane == 0) out[j] = 1.0f / (1.0f + expf(-(p + bl[0])));
}

extern "C" void kernel_launch(void* const* d_in, const int* in_sizes, int n_in,
                              void* d_out, int out_size, void* d_ws, size_t ws_size,
                              hipStream_t stream) {
    const float* x   = (const float*)d_in[0];
    const int*   ei  = (const int*)d_in[1];
    const int*   jix = (const int*)d_in[2];
    const float* ew  = (const float*)d_in[3];
    const float* W1  = (const float*)d_in[4];
    const float* b1  = (const float*)d_in[5];
    const float* W2  = (const float*)d_in[6];
    const float* b2  = (const float*)d_in[7];
    const float* Wl  = (const float*)d_in[8];
    const float* bl  = (const float*)d_in[9];
    float* out = (float*)d_out;
    const int* srcp = ei;
    const int* dstp = ei + N_EDGES;

    char* p = (char*)d_ws;
    auto alloc = [&](size_t bytes) {
        char* r = p;
        p += (bytes + 255) & ~(size_t)255;
        return r;
    };
    unsigned* gcnt  = (unsigned*)alloc((size_t)NB * 4);
    int*   bptr     = (int*)alloc((size_t)(NB + 1) * 4);
    int*   bcur     = (int*)alloc((size_t)NB * 4);
    int2*  bes      = (int2*)alloc((size_t)N_EDGES * 8);
    float* dis      = (float*)alloc((size_t)N_NODES * 4);
    int*   cnt      = (int*)alloc((size_t)(N_NODES + 1) * 4);
    int*   rowptr   = (int*)alloc((size_t)(N_NODES + 1) * 4);
    int*   bsums    = (int*)alloc(1024 * 4);
    int2*  erec     = (int2*)alloc((size_t)N_EDGES * 8);
    ushort_t* xw1b  = (ushort_t*)alloc((size_t)N_NODES * H1DIM * 2);
    float* h1       = (float*)alloc((size_t)N_NODES * H1DIM * 4);
    float* xw2      = (float*)alloc((size_t)N_NODES * H2DIM * 4);

    hipMemsetAsync(gcnt, 0, (size_t)NB * 4, stream);

    k_hist<<<256, 256, 0, stream>>>(dstp, gcnt);
    k_bscan<<<1, 256, 0, stream>>>(gcnt, bptr, bcur);
    k_bscatter<<<256, 256, 0, stream>>>(srcp, dstp, ew, bcur, bes);
    k_bdeg<<<NB, 256, 0, stream>>>(bptr, bes, cnt, dis);
    int nb = (N_NODES + 1023) / 1024;
    k_scan1<<<nb, 256, 0, stream>>>(cnt, rowptr, bsums);
    k_scan2<<<1, 64, 0, stream>>>(bsums, nb);
    k_scan3<<<(N_NODES + 255) / 256, 256, 0, stream>>>(rowptr, bsums);
    k_bfinal<<<NB, 256, 0, stream>>>(bptr, rowptr, bes, dis, erec);
    k_gemm1<<<(N_NODES + 63) / 64, 256, 0, stream>>>(x, W1, xw1b);
    k_agg1<<<(N_NODES + 3) / 4, 256, 0, stream>>>(xw1b, dis, rowptr, erec, b1, h1);
    k_gemm2<<<(N_NODES + 63) / 64, 256, 0, stream>>>(h1, W2, xw2);
    k_agg2<<<(BATCH + 3) / 4, 256, 0, stream>>>(xw2, dis, rowptr, erec, b2, jix, Wl, bl, out);
}